// Round 1
// baseline (639.295 us; speedup 1.0000x reference)
//
#include <hip/hip_runtime.h>

#define NPTS 40000
#define KNBR 32
#define CDIM 256
#define NH 8
#define HD 32

static constexpr float QK_SCALE = 0.17677669529663687f; // 32^-0.5

// ---------------- Kernel 1: fused QKV projection with sort-gather ----------------
// grid = NPTS/32 blocks, 256 threads. Block computes 32 sorted rows x 256 cols x {q,k,v}.
// Input tile staged transposed in LDS: in_t[c][r], pad 40 (16B-aligned rows, 4-way write conflict only).
__global__ __launch_bounds__(256, 2) void qkv_kernel(
    const float* __restrict__ qf,
    const float* __restrict__ Wq, const float* __restrict__ bq,
    const float* __restrict__ Wk, const float* __restrict__ bk,
    const float* __restrict__ Wv, const float* __restrict__ bv,
    const int* __restrict__ sort_idx,
    float* __restrict__ qs, float* __restrict__ ks, float* __restrict__ vs)
{
    __shared__ float in_t[CDIM][40];
    const int t = threadIdx.x;
    const int row0 = blockIdx.x * 32;

    #pragma unroll 8
    for (int r = 0; r < 32; ++r) {
        int src = sort_idx[row0 + r];          // uniform -> scalar load
        in_t[t][r] = qf[src * CDIM + t];       // coalesced 1KB row load
    }
    __syncthreads();

    float accq[32], acck[32], accv[32];
    #pragma unroll
    for (int r = 0; r < 32; ++r) { accq[r] = 0.f; acck[r] = 0.f; accv[r] = 0.f; }

    #pragma unroll 2
    for (int c = 0; c < CDIM; ++c) {
        float wq = Wq[c * CDIM + t];           // coalesced, L2-hot (256KB each)
        float wk = Wk[c * CDIM + t];
        float wv = Wv[c * CDIM + t];
        #pragma unroll
        for (int r4 = 0; r4 < 8; ++r4) {
            const float4 a = *reinterpret_cast<const float4*>(&in_t[c][r4 * 4]); // wave-broadcast
            const float av[4] = {a.x, a.y, a.z, a.w};
            #pragma unroll
            for (int i = 0; i < 4; ++i) {
                accq[r4 * 4 + i] = fmaf(av[i], wq, accq[r4 * 4 + i]);
                acck[r4 * 4 + i] = fmaf(av[i], wk, acck[r4 * 4 + i]);
                accv[r4 * 4 + i] = fmaf(av[i], wv, accv[r4 * 4 + i]);
            }
        }
    }

    const float bqv = bq[t], bkv = bk[t], bvv = bv[t];
    #pragma unroll
    for (int r = 0; r < 32; ++r) {
        int row = row0 + r;
        qs[row * CDIM + t] = (accq[r] + bqv) * QK_SCALE;  // fold attention scale into q
        ks[row * CDIM + t] = acck[r] + bkv;
        vs[row * CDIM + t] = accv[r] + bvv;
    }
}

// ---------------- Kernel 2: per-query attention (32 neighbors, 8 heads) ----------------
// grid = NPTS blocks, 256 threads. Stage 32 k-rows + 32 v-rows in LDS (pad 257: conflict-free).
__global__ __launch_bounds__(256, 2) void attn_kernel(
    const float* __restrict__ qs, const float* __restrict__ ks, const float* __restrict__ vs,
    const int* __restrict__ index_1, const int* __restrict__ sort_idx,
    float* __restrict__ x)
{
    __shared__ float k_s[KNBR][CDIM + 1];
    __shared__ float v_s[KNBR][CDIM + 1];
    __shared__ float q_s[CDIM];
    __shared__ float p_s[KNBR][NH + 1];

    const int n = blockIdx.x;
    const int t = threadIdx.x;

    q_s[t] = qs[n * CDIM + t];
    #pragma unroll 8
    for (int r = 0; r < KNBR; ++r) {
        int nb = index_1[n * KNBR + r];        // uniform -> scalar load
        k_s[r][t] = ks[nb * CDIM + t];         // coalesced 1KB gather rows
        v_s[r][t] = vs[nb * CDIM + t];
    }
    __syncthreads();

    // step 1: thread (h = t>>5, j = t&31) computes attn[j][h] = q[h,:] . k_j[h,:]
    {
        const int j = t & 31, h = t >> 5;
        float qreg[HD];
        #pragma unroll
        for (int d4 = 0; d4 < HD / 4; ++d4) {
            const float4 qa = *reinterpret_cast<const float4*>(&q_s[h * HD + d4 * 4]);
            qreg[d4 * 4 + 0] = qa.x; qreg[d4 * 4 + 1] = qa.y;
            qreg[d4 * 4 + 2] = qa.z; qreg[d4 * 4 + 3] = qa.w;
        }
        float acc = 0.f;
        #pragma unroll
        for (int d = 0; d < HD; ++d)
            acc = fmaf(qreg[d], k_s[j][h * HD + d], acc);

        // softmax over j within each 32-lane group (two heads per wave)
        float m = acc;
        #pragma unroll
        for (int off = 16; off > 0; off >>= 1)
            m = fmaxf(m, __shfl_xor(m, off));
        float e = __expf(acc - m);
        float ssum = e;
        #pragma unroll
        for (int off = 16; off > 0; off >>= 1)
            ssum += __shfl_xor(ssum, off);
        p_s[j][h] = e / ssum;
    }
    __syncthreads();

    // step 2: thread (h = t>>5, d = t&31) computes out[h][d] = sum_j p[j][h] * v_j[h][d]
    {
        const int h = t >> 5;
        float o = 0.f;
        #pragma unroll
        for (int jj = 0; jj < KNBR; ++jj)
            o = fmaf(p_s[jj][h], v_s[jj][t], o);
        const int orig = sort_idx[n];          // uniform -> scalar load
        x[orig * CDIM + t] = o;                // coalesced scatter row
    }
}

// ---------------- Kernel 3: output projection (x aliased with out is safe per-block) ----
// grid = NPTS/32 blocks, 256 threads. Thread = 2 cols x 16 rows.
__global__ __launch_bounds__(256, 2) void proj_kernel(
    const float* x, const float* __restrict__ Wp, const float* __restrict__ bp,
    float* out)
{
    __shared__ float in_t[CDIM][40];
    const int t = threadIdx.x;
    const int row0 = blockIdx.x * 32;

    #pragma unroll 8
    for (int r = 0; r < 32; ++r)
        in_t[t][r] = x[(row0 + r) * CDIM + t];
    __syncthreads();

    const int c0 = (t & 127) * 2;
    const int rh = (t >> 7) * 16;              // wave-uniform (waves 0,1 -> 0; 2,3 -> 16)
    float acc0[16], acc1[16];
    #pragma unroll
    for (int r = 0; r < 16; ++r) { acc0[r] = 0.f; acc1[r] = 0.f; }

    #pragma unroll 2
    for (int c = 0; c < CDIM; ++c) {
        const float2 w = *reinterpret_cast<const float2*>(&Wp[c * CDIM + c0]);
        #pragma unroll
        for (int r4 = 0; r4 < 4; ++r4) {
            const float4 a = *reinterpret_cast<const float4*>(&in_t[c][rh + r4 * 4]); // broadcast
            const float av[4] = {a.x, a.y, a.z, a.w};
            #pragma unroll
            for (int i = 0; i < 4; ++i) {
                acc0[r4 * 4 + i] = fmaf(av[i], w.x, acc0[r4 * 4 + i]);
                acc1[r4 * 4 + i] = fmaf(av[i], w.y, acc1[r4 * 4 + i]);
            }
        }
    }

    const float b0 = bp[c0], b1 = bp[c0 + 1];
    #pragma unroll
    for (int r = 0; r < 16; ++r) {
        float2 o;
        o.x = acc0[r] + b0;
        o.y = acc1[r] + b1;
        *reinterpret_cast<float2*>(&out[(row0 + rh + r) * CDIM + c0]) = o;
    }
}

extern "C" void kernel_launch(void* const* d_in, const int* in_sizes, int n_in,
                              void* d_out, int out_size, void* d_ws, size_t ws_size,
                              hipStream_t stream) {
    const float* qf  = (const float*)d_in[0];
    const float* Wq  = (const float*)d_in[1];
    const float* bq  = (const float*)d_in[2];
    const float* Wk  = (const float*)d_in[3];
    const float* bk  = (const float*)d_in[4];
    const float* Wv  = (const float*)d_in[5];
    const float* bv  = (const float*)d_in[6];
    const float* Wp  = (const float*)d_in[7];
    const float* bp  = (const float*)d_in[8];
    // d_in[9] = index_0 (unused: segment m -> query m/32 by construction)
    const int* index_1  = (const int*)d_in[10];
    const int* sort_idx = (const int*)d_in[11];
    float* out = (float*)d_out;

    float* qs = (float*)d_ws;                 // N*C f32, sorted order
    float* ks = qs + (size_t)NPTS * CDIM;
    float* vs = ks + (size_t)NPTS * CDIM;     // total ws use: 3*N*C*4 = 122.9 MB

    qkv_kernel<<<NPTS / 32, 256, 0, stream>>>(qf, Wq, bq, Wk, bk, Wv, bv, sort_idx, qs, ks, vs);
    attn_kernel<<<NPTS, 256, 0, stream>>>(qs, ks, vs, index_1, sort_idx, out);
    proj_kernel<<<NPTS / 32, 256, 0, stream>>>(out, Wp, bp, out);
}